// Round 2
// baseline (510.513 us; speedup 1.0000x reference)
//
#include <hip/hip_runtime.h>

typedef __attribute__((ext_vector_type(8))) short short8;
typedef __attribute__((ext_vector_type(4))) float f32x4;
typedef __attribute__((ext_vector_type(4))) unsigned short u16x4;

typedef const __attribute__((address_space(1))) void* gas_t;
typedef __attribute__((address_space(3))) void* las_t;

__device__ inline unsigned short f2bf(float x) {
    union { float f; unsigned u; } v; v.f = x;
    unsigned r = v.u + 0x7fffu + ((v.u >> 16) & 1u);
    return (unsigned short)(r >> 16);
}
__device__ inline float bf2f(unsigned short h) {
    union { unsigned u; float f; } v; v.u = ((unsigned)h) << 16;
    return v.f;
}

// ============================ PREP KERNELS ==================================

__global__ __launch_bounds__(256)
void convert_hl(const float* __restrict__ x, unsigned short* __restrict__ h,
                unsigned short* __restrict__ l)
{
    const long i = ((long)blockIdx.x * 256 + threadIdx.x) * 4;
    const float4 v = *(const float4*)(x + i);
    u16x4 hh, ll;
    hh[0] = f2bf(v.x); hh[1] = f2bf(v.y); hh[2] = f2bf(v.z); hh[3] = f2bf(v.w);
    ll[0] = f2bf(v.x - bf2f(hh[0])); ll[1] = f2bf(v.y - bf2f(hh[1]));
    ll[2] = f2bf(v.z - bf2f(hh[2])); ll[3] = f2bf(v.w - bf2f(hh[3]));
    *(u16x4*)(h + i) = hh;
    *(u16x4*)(l + i) = ll;
}

__global__ void prep_W(const float* __restrict__ W, unsigned short* __restrict__ W_h,
                       unsigned short* __restrict__ Wt_h, unsigned short* __restrict__ Wt_l)
{
    __shared__ float tile[32][33];
    const int e0 = blockIdx.x * 32, f0 = blockIdx.y * 32;
    const int tx = threadIdx.x, ty = threadIdx.y;
    for (int i = ty; i < 32; i += 8) {
        const float v = W[(long)(e0 + i) * 1024 + f0 + tx];
        tile[i][tx] = v;
        W_h[(long)(e0 + i) * 1024 + f0 + tx] = f2bf(v);
    }
    __syncthreads();
    for (int i = ty; i < 32; i += 8) {
        const float v = tile[tx][i];  // = W[e0+tx][f0+i]
        const unsigned short h = f2bf(v);
        Wt_h[(long)(f0 + i) * 1024 + e0 + tx] = h;
        Wt_l[(long)(f0 + i) * 1024 + e0 + tx] = f2bf(v - bf2f(h));
    }
}

__global__ void prep_sent(const float* __restrict__ sent,
                          unsigned short* __restrict__ s_h, unsigned short* __restrict__ s_l,
                          unsigned short* __restrict__ sT)
{
    __shared__ float tile[32][33];
    const int b = blockIdx.z;
    const int n0 = blockIdx.x * 32, e0 = blockIdx.y * 32;
    const float* src = sent + (long)b * 512 * 1024;
    const int tx = threadIdx.x, ty = threadIdx.y;
    for (int i = ty; i < 32; i += 8) {
        const float v = src[(long)(n0 + i) * 1024 + e0 + tx];
        tile[i][tx] = v;
        const unsigned short h = f2bf(v);
        s_h[(long)b * 512 * 1024 + (long)(n0 + i) * 1024 + e0 + tx] = h;
        s_l[(long)b * 512 * 1024 + (long)(n0 + i) * 1024 + e0 + tx] = f2bf(v - bf2f(h));
    }
    __syncthreads();
    for (int i = ty; i < 32; i += 8)
        sT[(long)b * 1024 * 512 + (long)(e0 + i) * 512 + n0 + tx] = f2bf(tile[tx][i]);
}

// ============================ GEMM (m97 structure) ==========================
template<bool SPLIT, bool EPI_HL>
__global__ __launch_bounds__(256, 2)
void gemm_k(const unsigned short* __restrict__ Ahg, const unsigned short* __restrict__ Alg,
            long sA, int lda,
            const unsigned short* __restrict__ Bhg, const unsigned short* __restrict__ Blg,
            long sB, int ldb,
            float* __restrict__ C, long sC, int ldc,
            float* __restrict__ C2, long sC2, int ldc2,
            unsigned short* __restrict__ Oh, unsigned short* __restrict__ Ol,
            long sO, int ldo,
            int K)
{
    extern __shared__ unsigned short lds[];
    unsigned short* AhL = lds;
    unsigned short* BhL = lds + 128 * 32;
    unsigned short* AlL = SPLIT ? lds + 2 * 128 * 32 : nullptr;
    unsigned short* BlL = SPLIT ? lds + 3 * 128 * 32 : nullptr;

    const int tid = threadIdx.x;
    const long bz = blockIdx.z;
    const long m0 = (long)blockIdx.x * 128;
    const long n0 = (long)blockIdx.y * 128;

    const int lane = tid & 63, wave = tid >> 6;
    const int wm = (wave >> 1) * 64, wn = (wave & 1) * 64;
    const int fr = lane & 15, kq = lane >> 4, k0 = kq * 8;

    const int drow = lane >> 2, dcol = (lane & 3) * 8;

    const unsigned short* Ah = Ahg + bz * sA;
    const unsigned short* Bh = Bhg + bz * sB;
    const unsigned short* Al = SPLIT ? Alg + bz * sA : nullptr;
    const unsigned short* Bl = SPLIT ? Blg + bz * sB : nullptr;

    f32x4 acc[4][4] = {};

    for (int kb = 0; kb < K; kb += 32) {
        #pragma unroll
        for (int r = 0; r < 2; ++r) {
            const int rb = r * 64 + wave * 16;
            __builtin_amdgcn_global_load_lds(
                (gas_t)(Ah + (m0 + rb + drow) * (long)lda + kb + dcol),
                (las_t)(AhL + rb * 32), 16, 0, 0);
            __builtin_amdgcn_global_load_lds(
                (gas_t)(Bh + (n0 + rb + drow) * (long)ldb + kb + dcol),
                (las_t)(BhL + rb * 32), 16, 0, 0);
            if constexpr (SPLIT) {
                __builtin_amdgcn_global_load_lds(
                    (gas_t)(Al + (m0 + rb + drow) * (long)lda + kb + dcol),
                    (las_t)(AlL + rb * 32), 16, 0, 0);
                __builtin_amdgcn_global_load_lds(
                    (gas_t)(Bl + (n0 + rb + drow) * (long)ldb + kb + dcol),
                    (las_t)(BlL + rb * 32), 16, 0, 0);
            }
        }
        __syncthreads();

        short8 af[4], bfr[4], alf[4], blf[4];
        #pragma unroll
        for (int t = 0; t < 4; ++t) {
            af[t]  = *(const short8*)(AhL + (wm + t * 16 + fr) * 32 + k0);
            bfr[t] = *(const short8*)(BhL + (wn + t * 16 + fr) * 32 + k0);
            if constexpr (SPLIT) {
                alf[t] = *(const short8*)(AlL + (wm + t * 16 + fr) * 32 + k0);
                blf[t] = *(const short8*)(BlL + (wn + t * 16 + fr) * 32 + k0);
            }
        }
        #pragma unroll
        for (int mt = 0; mt < 4; ++mt)
            #pragma unroll
            for (int nt = 0; nt < 4; ++nt) {
                acc[mt][nt] = __builtin_amdgcn_mfma_f32_16x16x32_bf16(af[mt], bfr[nt], acc[mt][nt], 0, 0, 0);
                if constexpr (SPLIT) {
                    acc[mt][nt] = __builtin_amdgcn_mfma_f32_16x16x32_bf16(alf[mt], bfr[nt], acc[mt][nt], 0, 0, 0);
                    acc[mt][nt] = __builtin_amdgcn_mfma_f32_16x16x32_bf16(af[mt], blf[nt], acc[mt][nt], 0, 0, 0);
                }
            }
        __syncthreads();
    }

    #pragma unroll
    for (int mt = 0; mt < 4; ++mt) {
        const long rowb = m0 + wm + mt * 16 + kq * 4;
        #pragma unroll
        for (int nt = 0; nt < 4; ++nt) {
            const long col = n0 + wn + nt * 16 + fr;
            #pragma unroll
            for (int i = 0; i < 4; ++i) {
                const float v = acc[mt][nt][i];
                if constexpr (EPI_HL) {
                    const unsigned short h = f2bf(v);
                    Oh[bz * sO + (rowb + i) * ldo + col] = h;
                    Ol[bz * sO + (rowb + i) * ldo + col] = f2bf(v - bf2f(h));
                } else {
                    C[bz * sC + (rowb + i) * ldc + col] = v;
                    if (C2) C2[bz * sC2 + (rowb + i) * ldc2 + col] = v;
                }
            }
        }
    }
}

// ===================== FUSED ATTENTION (scores+softmax+PV) ==================
// v2: phase 1 is BARRIER-FREE and LDS-FREE. Fragments load directly
// global->VGPR: each wave reads only its own 64 V rows (bf16 hi/lo, L2-resident
// per XCD since blockIdx.x = batch = XCD), and the shared 64 Q rows (L1-hit
// after first wave). Latency hidden by ILP (compiler-pipelined vmcnt-counted
// loads across unrolled K-steps), not barriers -- fixes the 1-block/CU
// exposed-latency stall (round-1: MfmaUtil 20%, 4.9M LDS bank conflicts).
//
// Phase 2: exact softmax (shfl over fr lanes + LDS cross-wave reduce).
// Phase 3: P (bf16) -> LDS [64][520].
// Phase 4: G = P @ sentT^T; A-frags from LDS P, B-frags direct from global.
__global__ __launch_bounds__(512, 2)
void attn_fused(const unsigned short* __restrict__ Qh, const unsigned short* __restrict__ Ql,
                const unsigned short* __restrict__ Vh, const unsigned short* __restrict__ Vl,
                const unsigned short* __restrict__ sT,
                float* __restrict__ gout, float* __restrict__ comb)
{
    extern __shared__ unsigned short lds[];
    // layout (shorts): [0,33280)      P[64][520]
    //                  [33280,34304)  wred[64][8] f32
    //                  [34304,34432)  rstat[64]   f32     => 68864 B total
    unsigned short* P = lds;
    float* wred  = (float*)(lds + 33280);
    float* rstat = (float*)(lds + 34304);

    const int tid  = threadIdx.x;
    const int lane = tid & 63, wave = tid >> 6;
    const int fr = lane & 15, kq = lane >> 4, k0 = kq * 8;
    const int wn = wave * 64;

    const long b  = blockIdx.x;              // batch -> XCD (bid % 8)
    const long r0 = (long)blockIdx.y * 64;   // Q row block

    // per-lane fragment base pointers (row = fr, k-chunk = kq)
    const unsigned short* qh = Qh + (b * 2048 + r0 + fr) * 1024 + k0;
    const unsigned short* ql = Ql + (b * 2048 + r0 + fr) * 1024 + k0;
    const unsigned short* vh = Vh + (b * 512 + wn + fr) * 1024 + k0;
    const unsigned short* vl = Vl + (b * 512 + wn + fr) * 1024 + k0;

    // ---------------- phase 1: S = Q @ V^T (split, no LDS, no barriers) -----
    f32x4 acc[4][4] = {};
    #pragma unroll 2
    for (int kb = 0; kb < 1024; kb += 32) {
        short8 ah[4], al[4], bh[4], bl[4];
        #pragma unroll
        for (int t = 0; t < 4; ++t) {
            ah[t] = *(const short8*)(qh + t * 16 * 1024 + kb);
            al[t] = *(const short8*)(ql + t * 16 * 1024 + kb);
            bh[t] = *(const short8*)(vh + t * 16 * 1024 + kb);
            bl[t] = *(const short8*)(vl + t * 16 * 1024 + kb);
        }
        #pragma unroll
        for (int mt = 0; mt < 4; ++mt)
            #pragma unroll
            for (int nt = 0; nt < 4; ++nt) {
                acc[mt][nt] = __builtin_amdgcn_mfma_f32_16x16x32_bf16(ah[mt], bh[nt], acc[mt][nt], 0, 0, 0);
                acc[mt][nt] = __builtin_amdgcn_mfma_f32_16x16x32_bf16(al[mt], bh[nt], acc[mt][nt], 0, 0, 0);
                acc[mt][nt] = __builtin_amdgcn_mfma_f32_16x16x32_bf16(ah[mt], bl[nt], acc[mt][nt], 0, 0, 0);
            }
    }

    // ---------------- phase 2: exact row softmax ----------------
    // lane holds rows {mt*16+kq*4+i}, cols {64*wave + nt*16 + fr}
    float rmx[4][4];
    #pragma unroll
    for (int mt = 0; mt < 4; ++mt)
        #pragma unroll
        for (int i = 0; i < 4; ++i) {
            float m = fmaxf(fmaxf(acc[mt][0][i], acc[mt][1][i]),
                            fmaxf(acc[mt][2][i], acc[mt][3][i]));
            #pragma unroll
            for (int off = 1; off <= 8; off <<= 1)
                m = fmaxf(m, __shfl_xor(m, off));      // reduce over fr (bits 0-3)
            rmx[mt][i] = m;
        }
    if (fr == 0) {
        #pragma unroll
        for (int mt = 0; mt < 4; ++mt)
            #pragma unroll
            for (int i = 0; i < 4; ++i)
                wred[(mt * 16 + kq * 4 + i) * 8 + wave] = rmx[mt][i];
    }
    __syncthreads();
    if (tid < 64) {
        float m = wred[tid * 8];
        #pragma unroll
        for (int w = 1; w < 8; ++w) m = fmaxf(m, wred[tid * 8 + w]);
        rstat[tid] = m;
    }
    __syncthreads();

    #pragma unroll
    for (int mt = 0; mt < 4; ++mt)
        #pragma unroll
        for (int i = 0; i < 4; ++i) {
            const float m = rstat[mt * 16 + kq * 4 + i];
            float s = 0.f;
            #pragma unroll
            for (int nt = 0; nt < 4; ++nt) {
                const float e = __expf(acc[mt][nt][i] - m);
                acc[mt][nt][i] = e;
                s += e;
            }
            #pragma unroll
            for (int off = 1; off <= 8; off <<= 1) s += __shfl_xor(s, off);
            rmx[mt][i] = s;   // wave-partial sums
        }
    if (fr == 0) {
        #pragma unroll
        for (int mt = 0; mt < 4; ++mt)
            #pragma unroll
            for (int i = 0; i < 4; ++i)
                wred[(mt * 16 + kq * 4 + i) * 8 + wave] = rmx[mt][i];
    }
    __syncthreads();
    if (tid < 64) {
        float s = wred[tid * 8];
        #pragma unroll
        for (int w = 1; w < 8; ++w) s += wred[tid * 8 + w];
        rstat[tid] = 1.0f / s;   // overwrite rmax (all reads done)
    }
    __syncthreads();

    // ---------------- phase 3: P (bf16) -> LDS ----------------
    #pragma unroll
    for (int mt = 0; mt < 4; ++mt)
        #pragma unroll
        for (int i = 0; i < 4; ++i) {
            const int row = mt * 16 + kq * 4 + i;
            const float inv = rstat[row];
            #pragma unroll
            for (int nt = 0; nt < 4; ++nt)
                P[row * 520 + wn + nt * 16 + fr] = f2bf(acc[mt][nt][i] * inv);
        }
    __syncthreads();

    // ---------------- phase 4: G = P @ sentT^T ----------------
    const unsigned short* sTb = sT + b * 1024 * 512;
    const int e0 = wave * 128;
    const unsigned short* sb = sTb + (long)(e0 + fr) * 512 + k0;
    const unsigned short* pP = P + fr * 520 + k0;

    f32x4 acc2[4][8] = {};
    #pragma unroll 2
    for (int kb = 0; kb < 512; kb += 32) {
        short8 pa[4], pb[8];
        #pragma unroll
        for (int mt = 0; mt < 4; ++mt)
            pa[mt] = *(const short8*)(pP + mt * 16 * 520 + kb);
        #pragma unroll
        for (int nt = 0; nt < 8; ++nt)
            pb[nt] = *(const short8*)(sb + nt * 16 * 512 + kb);
        #pragma unroll
        for (int mt = 0; mt < 4; ++mt)
            #pragma unroll
            for (int nt = 0; nt < 8; ++nt)
                acc2[mt][nt] = __builtin_amdgcn_mfma_f32_16x16x32_bf16(pa[mt], pb[nt], acc2[mt][nt], 0, 0, 0);
    }

    float* gb = gout + (b * 2048 + r0) * 1024;
    float* cb = comb + (b * 2048 + r0) * 2048 + 1024;
    #pragma unroll
    for (int mt = 0; mt < 4; ++mt) {
        const int rowb = mt * 16 + kq * 4;
        #pragma unroll
        for (int nt = 0; nt < 8; ++nt) {
            const int col = e0 + nt * 16 + fr;
            #pragma unroll
            for (int i = 0; i < 4; ++i) {
                const float v = acc2[mt][nt][i];
                gb[(long)(rowb + i) * 1024 + col] = v;
                cb[(long)(rowb + i) * 2048 + col] = v;
            }
        }
    }
}

// ============================ FALLBACK PATH (round-1) ========================

template<bool SPLIT>
__global__ __launch_bounds__(256, 2)
void gemm_bt(const float* __restrict__ A, long sA, int lda,
             const float* __restrict__ B, long sB, int ldb,
             float* __restrict__ C, long sC, int ldc,
             float* __restrict__ C2, long sC2, int ldc2,
             int K)
{
    constexpr int LDS_S = 40;
    extern __shared__ unsigned short lds[];
    unsigned short* Ah = lds;
    unsigned short* Bh = lds + 128 * LDS_S;
    unsigned short* Al = SPLIT ? (lds + 2 * 128 * LDS_S) : nullptr;
    unsigned short* Bl = SPLIT ? (lds + 3 * 128 * LDS_S) : nullptr;

    const int tid = threadIdx.x;
    const int bz = blockIdx.z;
    A += (long)bz * sA; B += (long)bz * sB; C += (long)bz * sC;
    if (C2) C2 += (long)bz * sC2;
    const long m0 = (long)blockIdx.x * 128;
    const long n0 = (long)blockIdx.y * 128;

    const int lane = tid & 63, wave = tid >> 6;
    const int wm = (wave >> 1) * 64, wn = (wave & 1) * 64;
    const int fr = lane & 15, kq = lane >> 4, k0 = kq * 8;
    const int sc4 = (tid & 7) * 4;
    const int sr  = tid >> 3;

    f32x4 acc[4][4] = {};

    for (int kb = 0; kb < K; kb += 32) {
        #pragma unroll
        for (int p = 0; p < 4; ++p) {
            const int row = p * 32 + sr;
            const float4 va = *(const float4*)(A + (m0 + row) * lda + kb + sc4);
            const float4 vb = *(const float4*)(B + (n0 + row) * ldb + kb + sc4);
            u16x4 ah; ah[0] = f2bf(va.x); ah[1] = f2bf(va.y); ah[2] = f2bf(va.z); ah[3] = f2bf(va.w);
            u16x4 bh; bh[0] = f2bf(vb.x); bh[1] = f2bf(vb.y); bh[2] = f2bf(vb.z); bh[3] = f2bf(vb.w);
            *(u16x4*)(Ah + row * LDS_S + sc4) = ah;
            *(u16x4*)(Bh + row * LDS_S + sc4) = bh;
            if constexpr (SPLIT) {
                u16x4 al; al[0] = f2bf(va.x - bf2f(ah[0])); al[1] = f2bf(va.y - bf2f(ah[1]));
                          al[2] = f2bf(va.z - bf2f(ah[2])); al[3] = f2bf(va.w - bf2f(ah[3]));
                u16x4 bl; bl[0] = f2bf(vb.x - bf2f(bh[0])); bl[1] = f2bf(vb.y - bf2f(bh[1]));
                          bl[2] = f2bf(vb.z - bf2f(bh[2])); bl[3] = f2bf(vb.w - bf2f(bh[3]));
                *(u16x4*)(Al + row * LDS_S + sc4) = al;
                *(u16x4*)(Bl + row * LDS_S + sc4) = bl;
            }
        }
        __syncthreads();

        short8 af[4], bfr[4], alf[4], blf[4];
        #pragma unroll
        for (int t = 0; t < 4; ++t) {
            af[t]  = *(const short8*)(Ah + (wm + t * 16 + fr) * LDS_S + k0);
            bfr[t] = *(const short8*)(Bh + (wn + t * 16 + fr) * LDS_S + k0);
            if constexpr (SPLIT) {
                alf[t] = *(const short8*)(Al + (wm + t * 16 + fr) * LDS_S + k0);
                blf[t] = *(const short8*)(Bl + (wn + t * 16 + fr) * LDS_S + k0);
            }
        }
        #pragma unroll
        for (int mt = 0; mt < 4; ++mt)
            #pragma unroll
            for (int nt = 0; nt < 4; ++nt) {
                acc[mt][nt] = __builtin_amdgcn_mfma_f32_16x16x32_bf16(af[mt], bfr[nt], acc[mt][nt], 0, 0, 0);
                if constexpr (SPLIT) {
                    acc[mt][nt] = __builtin_amdgcn_mfma_f32_16x16x32_bf16(alf[mt], bfr[nt], acc[mt][nt], 0, 0, 0);
                    acc[mt][nt] = __builtin_amdgcn_mfma_f32_16x16x32_bf16(af[mt], blf[nt], acc[mt][nt], 0, 0, 0);
                }
            }
        __syncthreads();
    }

    #pragma unroll
    for (int mt = 0; mt < 4; ++mt) {
        const long rowb = m0 + wm + mt * 16 + kq * 4;
        #pragma unroll
        for (int nt = 0; nt < 4; ++nt) {
            const long col = n0 + wn + nt * 16 + fr;
            #pragma unroll
            for (int i = 0; i < 4; ++i) {
                C[(rowb + i) * ldc + col] = acc[mt][nt][i];
                if (C2) C2[(rowb + i) * ldc2 + col] = acc[mt][nt][i];
            }
        }
    }
}

__global__ __launch_bounds__(256)
void softmax_rows(float* __restrict__ S)
{
    const int wave = threadIdx.x >> 6, lane = threadIdx.x & 63;
    const long row = (long)blockIdx.x * 4 + wave;
    float* p = S + row * 512 + lane * 8;
    float4 v0 = *(float4*)p;
    float4 v1 = *(float4*)(p + 4);
    float m = fmaxf(fmaxf(fmaxf(v0.x, v0.y), fmaxf(v0.z, v0.w)),
                    fmaxf(fmaxf(v1.x, v1.y), fmaxf(v1.z, v1.w)));
    #pragma unroll
    for (int off = 32; off > 0; off >>= 1) m = fmaxf(m, __shfl_xor(m, off));
    v0.x = __expf(v0.x - m); v0.y = __expf(v0.y - m);
    v0.z = __expf(v0.z - m); v0.w = __expf(v0.w - m);
    v1.x = __expf(v1.x - m); v1.y = __expf(v1.y - m);
    v1.z = __expf(v1.z - m); v1.w = __expf(v1.w - m);
    float s = v0.x + v0.y + v0.z + v0.w + v1.x + v1.y + v1.z + v1.w;
    #pragma unroll
    for (int off = 32; off > 0; off >>= 1) s += __shfl_xor(s, off);
    const float inv = 1.0f / s;
    v0.x *= inv; v0.y *= inv; v0.z *= inv; v0.w *= inv;
    v1.x *= inv; v1.y *= inv; v1.z *= inv; v1.w *= inv;
    *(float4*)p = v0;
    *(float4*)(p + 4) = v1;
}

__global__ void transpose_bn(const float* __restrict__ in, float* __restrict__ out)
{
    __shared__ float tile[32][33];
    const int b = blockIdx.z;
    const int n0 = blockIdx.x * 32, e0 = blockIdx.y * 32;
    const float* src = in + (long)b * 512 * 1024;
    float* dst = out + (long)b * 1024 * 512;
    const int tx = threadIdx.x, ty = threadIdx.y;
    for (int i = ty; i < 32; i += 8)
        tile[i][tx] = src[(long)(n0 + i) * 1024 + e0 + tx];
    __syncthreads();
    for (int i = ty; i < 32; i += 8)
        dst[(long)(e0 + i) * 512 + n0 + tx] = tile[tx][i];
}

// ============================ LAUNCH ========================================

extern "C" void kernel_launch(void* const* d_in, const int* in_sizes, int n_in,
                              void* d_out, int out_size, void* d_ws, size_t ws_size,
                              hipStream_t stream)
{
    const float* word = (const float*)d_in[0];  // (8,2048,1024)
    const float* sent = (const float*)d_in[1];  // (8,512,1024)
    const float* W    = (const float*)d_in[2];  // (1024,1024)
    float* out  = (float*)d_out;
    float* comb = out;                              // (8,2048,2048)
    float* gout = out + (long)8 * 2048 * 2048;      // (8,2048,1024)

    const size_t MB = 1ull << 20;

    if (ws_size >= 110 * MB) {
        // -------- fast path: V = sent@W re-decomposition + fused attention --------
        char* w8 = (char*)d_ws;
        unsigned short* word_h = (unsigned short*)(w8);             // 32 MB [0,32)
        unsigned short* word_l = (unsigned short*)(w8 + 32 * MB);   // 32 MB [32,64)
        unsigned short* V_h    = (unsigned short*)(w8 + 64 * MB);   //  8 MB [64,72)
        unsigned short* V_l    = (unsigned short*)(w8 + 72 * MB);   //  8 MB [72,80)
        unsigned short* sentT  = (unsigned short*)(w8 + 80 * MB);   //  8 MB [80,88)
        unsigned short* sent_h = (unsigned short*)(w8 + 88 * MB);   //  8 MB [88,96)  dead after V-GEMM
        unsigned short* sent_l = (unsigned short*)(w8 + 96 * MB);   //  8 MB [96,104) dead after V-GEMM
        unsigned short* W_h    = (unsigned short*)(w8 + 104 * MB);  //  2 MB [104,106)
        unsigned short* Wt_h   = (unsigned short*)(w8 + 106 * MB);  //  2 MB [106,108)
        unsigned short* Wt_l   = (unsigned short*)(w8 + 108 * MB);  //  2 MB [108,110)

        // one-time: allow >64KB dynamic LDS for attn_fused (gfx950 has 160KB/CU)
        static bool attr_done = false;
        if (!attr_done) {
            (void)hipFuncSetAttribute((const void*)attn_fused,
                                      hipFuncAttributeMaxDynamicSharedMemorySize, 68864);
            attr_done = true;
        }

        convert_hl<<<16384, 256, 0, stream>>>(word, word_h, word_l);
        prep_W<<<dim3(32, 32), dim3(32, 8), 0, stream>>>(W, W_h, Wt_h, Wt_l);
        prep_sent<<<dim3(16, 32, 8), dim3(32, 8), 0, stream>>>(sent, sent_h, sent_l, sentT);

        const size_t lds4 = 4 * 128 * 32 * sizeof(unsigned short);  // 32 KB
        const size_t lds2 = 2 * 128 * 32 * sizeof(unsigned short);  // 16 KB

        // w = word @ W^T (PLAIN bf16) -> comb[:, :, 0:1024]
        gemm_k<false, false><<<dim3(128, 8, 1), 256, lds2, stream>>>(
            word_h, nullptr, 0L, 1024, W_h, nullptr, 0L, 1024,
            comb, 0L, 2048, nullptr, 0L, 0, nullptr, nullptr, 0L, 0, 1024);

        // V = sent @ W (SPLIT), batches merged in M (4096x1024), B=Wt shared
        gemm_k<true, true><<<dim3(32, 8, 1), 256, lds4, stream>>>(
            sent_h, sent_l, 0L, 1024, Wt_h, Wt_l, 0L, 1024,
            nullptr, 0L, 0, nullptr, 0L, 0, V_h, V_l, 0L, 1024, 1024);

        // fused: scores = word@V^T (split) -> softmax -> g = att@sent
        //        -> gout AND comb[:, :, 1024:2048]
        attn_fused<<<dim3(8, 32, 1), 512, 68864, stream>>>(
            word_h, word_l, V_h, V_l, sentT, gout, comb);
    } else {
        // -------- round-1 fallback (48 MB ws) --------
        float* scores = (float*)d_ws;                   // 32 MB
        float* sentT  = scores + (long)8 * 2048 * 512;  // 16 MB
        const size_t lds_split  = 4 * 128 * 40 * sizeof(unsigned short);
        const size_t lds_single = 2 * 128 * 40 * sizeof(unsigned short);

        transpose_bn<<<dim3(16, 32, 8), dim3(32, 8), 0, stream>>>(sent, sentT);
        gemm_bt<true><<<dim3(128, 8, 1), 256, lds_split, stream>>>(
            word, 0L, 1024, W, 0L, 1024, comb, 0L, 2048, nullptr, 0L, 0, 1024);
        gemm_bt<true><<<dim3(16, 4, 8), 256, lds_split, stream>>>(
            comb, (long)2048 * 2048, 2048, sent, (long)512 * 1024, 1024,
            scores, (long)2048 * 512, 512, nullptr, 0L, 0, 1024);
        softmax_rows<<<4096, 256, 0, stream>>>(scores);
        gemm_bt<false><<<dim3(16, 8, 8), 256, lds_single, stream>>>(
            scores, (long)2048 * 512, 512, sentT, (long)1024 * 512, 512,
            gout, (long)2048 * 1024, 1024, comb + 1024, (long)2048 * 2048, 2048, 512);
    }
}

// Round 3
// 455.169 us; speedup vs baseline: 1.1216x; 1.1216x over previous
//
#include <hip/hip_runtime.h>

typedef __attribute__((ext_vector_type(8))) short short8;
typedef __attribute__((ext_vector_type(4))) float f32x4;
typedef __attribute__((ext_vector_type(4))) unsigned short u16x4;

typedef const __attribute__((address_space(1))) void* gas_t;
typedef __attribute__((address_space(3))) void* las_t;

__device__ inline unsigned short f2bf(float x) {
    union { float f; unsigned u; } v; v.f = x;
    unsigned r = v.u + 0x7fffu + ((v.u >> 16) & 1u);
    return (unsigned short)(r >> 16);
}
__device__ inline float bf2f(unsigned short h) {
    union { unsigned u; float f; } v; v.u = ((unsigned)h) << 16;
    return v.f;
}

// ============================ PREP KERNELS ==================================

__global__ __launch_bounds__(256)
void convert_hl(const float* __restrict__ x, unsigned short* __restrict__ h,
                unsigned short* __restrict__ l)
{
    const long i = ((long)blockIdx.x * 256 + threadIdx.x) * 4;
    const float4 v = *(const float4*)(x + i);
    u16x4 hh, ll;
    hh[0] = f2bf(v.x); hh[1] = f2bf(v.y); hh[2] = f2bf(v.z); hh[3] = f2bf(v.w);
    ll[0] = f2bf(v.x - bf2f(hh[0])); ll[1] = f2bf(v.y - bf2f(hh[1]));
    ll[2] = f2bf(v.z - bf2f(hh[2])); ll[3] = f2bf(v.w - bf2f(hh[3]));
    *(u16x4*)(h + i) = hh;
    *(u16x4*)(l + i) = ll;
}

__global__ void prep_W(const float* __restrict__ W, unsigned short* __restrict__ W_h,
                       unsigned short* __restrict__ Wt_h, unsigned short* __restrict__ Wt_l)
{
    __shared__ float tile[32][33];
    const int e0 = blockIdx.x * 32, f0 = blockIdx.y * 32;
    const int tx = threadIdx.x, ty = threadIdx.y;
    for (int i = ty; i < 32; i += 8) {
        const float v = W[(long)(e0 + i) * 1024 + f0 + tx];
        tile[i][tx] = v;
        W_h[(long)(e0 + i) * 1024 + f0 + tx] = f2bf(v);
    }
    __syncthreads();
    for (int i = ty; i < 32; i += 8) {
        const float v = tile[tx][i];  // = W[e0+tx][f0+i]
        const unsigned short h = f2bf(v);
        Wt_h[(long)(f0 + i) * 1024 + e0 + tx] = h;
        Wt_l[(long)(f0 + i) * 1024 + e0 + tx] = f2bf(v - bf2f(h));
    }
}

__global__ void prep_sent(const float* __restrict__ sent,
                          unsigned short* __restrict__ s_h, unsigned short* __restrict__ s_l,
                          unsigned short* __restrict__ sT)
{
    __shared__ float tile[32][33];
    const int b = blockIdx.z;
    const int n0 = blockIdx.x * 32, e0 = blockIdx.y * 32;
    const float* src = sent + (long)b * 512 * 1024;
    const int tx = threadIdx.x, ty = threadIdx.y;
    for (int i = ty; i < 32; i += 8) {
        const float v = src[(long)(n0 + i) * 1024 + e0 + tx];
        tile[i][tx] = v;
        const unsigned short h = f2bf(v);
        s_h[(long)b * 512 * 1024 + (long)(n0 + i) * 1024 + e0 + tx] = h;
        s_l[(long)b * 512 * 1024 + (long)(n0 + i) * 1024 + e0 + tx] = f2bf(v - bf2f(h));
    }
    __syncthreads();
    for (int i = ty; i < 32; i += 8)
        sT[(long)b * 1024 * 512 + (long)(e0 + i) * 512 + n0 + tx] = f2bf(tile[tx][i]);
}

// ============================ GEMM (m97 structure) ==========================
template<bool SPLIT, bool EPI_HL>
__global__ __launch_bounds__(256, 2)
void gemm_k(const unsigned short* __restrict__ Ahg, const unsigned short* __restrict__ Alg,
            long sA, int lda,
            const unsigned short* __restrict__ Bhg, const unsigned short* __restrict__ Blg,
            long sB, int ldb,
            float* __restrict__ C, long sC, int ldc,
            float* __restrict__ C2, long sC2, int ldc2,
            unsigned short* __restrict__ Oh, unsigned short* __restrict__ Ol,
            long sO, int ldo,
            int K)
{
    extern __shared__ unsigned short lds[];
    unsigned short* AhL = lds;
    unsigned short* BhL = lds + 128 * 32;
    unsigned short* AlL = SPLIT ? lds + 2 * 128 * 32 : nullptr;
    unsigned short* BlL = SPLIT ? lds + 3 * 128 * 32 : nullptr;

    const int tid = threadIdx.x;
    const long bz = blockIdx.z;
    const long m0 = (long)blockIdx.x * 128;
    const long n0 = (long)blockIdx.y * 128;

    const int lane = tid & 63, wave = tid >> 6;
    const int wm = (wave >> 1) * 64, wn = (wave & 1) * 64;
    const int fr = lane & 15, kq = lane >> 4, k0 = kq * 8;

    const int drow = lane >> 2, dcol = (lane & 3) * 8;

    const unsigned short* Ah = Ahg + bz * sA;
    const unsigned short* Bh = Bhg + bz * sB;
    const unsigned short* Al = SPLIT ? Alg + bz * sA : nullptr;
    const unsigned short* Bl = SPLIT ? Blg + bz * sB : nullptr;

    f32x4 acc[4][4] = {};

    for (int kb = 0; kb < K; kb += 32) {
        #pragma unroll
        for (int r = 0; r < 2; ++r) {
            const int rb = r * 64 + wave * 16;
            __builtin_amdgcn_global_load_lds(
                (gas_t)(Ah + (m0 + rb + drow) * (long)lda + kb + dcol),
                (las_t)(AhL + rb * 32), 16, 0, 0);
            __builtin_amdgcn_global_load_lds(
                (gas_t)(Bh + (n0 + rb + drow) * (long)ldb + kb + dcol),
                (las_t)(BhL + rb * 32), 16, 0, 0);
            if constexpr (SPLIT) {
                __builtin_amdgcn_global_load_lds(
                    (gas_t)(Al + (m0 + rb + drow) * (long)lda + kb + dcol),
                    (las_t)(AlL + rb * 32), 16, 0, 0);
                __builtin_amdgcn_global_load_lds(
                    (gas_t)(Bl + (n0 + rb + drow) * (long)ldb + kb + dcol),
                    (las_t)(BlL + rb * 32), 16, 0, 0);
            }
        }
        __syncthreads();

        short8 af[4], bfr[4], alf[4], blf[4];
        #pragma unroll
        for (int t = 0; t < 4; ++t) {
            af[t]  = *(const short8*)(AhL + (wm + t * 16 + fr) * 32 + k0);
            bfr[t] = *(const short8*)(BhL + (wn + t * 16 + fr) * 32 + k0);
            if constexpr (SPLIT) {
                alf[t] = *(const short8*)(AlL + (wm + t * 16 + fr) * 32 + k0);
                blf[t] = *(const short8*)(BlL + (wn + t * 16 + fr) * 32 + k0);
            }
        }
        #pragma unroll
        for (int mt = 0; mt < 4; ++mt)
            #pragma unroll
            for (int nt = 0; nt < 4; ++nt) {
                acc[mt][nt] = __builtin_amdgcn_mfma_f32_16x16x32_bf16(af[mt], bfr[nt], acc[mt][nt], 0, 0, 0);
                if constexpr (SPLIT) {
                    acc[mt][nt] = __builtin_amdgcn_mfma_f32_16x16x32_bf16(alf[mt], bfr[nt], acc[mt][nt], 0, 0, 0);
                    acc[mt][nt] = __builtin_amdgcn_mfma_f32_16x16x32_bf16(af[mt], blf[nt], acc[mt][nt], 0, 0, 0);
                }
            }
        __syncthreads();
    }

    #pragma unroll
    for (int mt = 0; mt < 4; ++mt) {
        const long rowb = m0 + wm + mt * 16 + kq * 4;
        #pragma unroll
        for (int nt = 0; nt < 4; ++nt) {
            const long col = n0 + wn + nt * 16 + fr;
            #pragma unroll
            for (int i = 0; i < 4; ++i) {
                const float v = acc[mt][nt][i];
                if constexpr (EPI_HL) {
                    const unsigned short h = f2bf(v);
                    Oh[bz * sO + (rowb + i) * ldo + col] = h;
                    Ol[bz * sO + (rowb + i) * ldo + col] = f2bf(v - bf2f(h));
                } else {
                    C[bz * sC + (rowb + i) * ldc + col] = v;
                    if (C2) C2[bz * sC2 + (rowb + i) * ldc2 + col] = v;
                }
            }
        }
    }
}

// ===================== FUSED ATTENTION (scores+softmax+PV) ==================
// v3: phase 1 = double-buffered PIPELINED staging (T3+T4): issue next K-tile's
// global_load_lds BEFORE computing current tile; counted s_waitcnt vmcnt(9)
// (= loads just issued) + raw s_barrier -- never drains vmcnt(0) in the loop.
// Fixes round-1's exposed-latency drain (132us, MfmaUtil 20%) at 1 block/CU.
// LDS: 2 x 72KB stage buffers + reduce scratch = 149.7KB (1 block/CU).
// Bank-conflict fix (rule 21, both-sides): staging pre-swizzles the GLOBAL
// source 16B-chunk (c ^= row&3) writing LDS linearly; readers XOR the chunk
// back (kq ^ fr&3): 8-way ds_read_b128 conflict -> 4-way.
//
// Phase 2: exact softmax (shfl over fr lanes + LDS cross-wave reduce).
// Phase 3: P (bf16) -> LDS [64][520] (aliases dead stage buffer 0).
// Phase 4: G = P @ sentT^T; A-frags from LDS P, B-frags direct from global
//          (sentT L2-resident per XCD; no barriers in loop).
__global__ __launch_bounds__(512, 2)
void attn_fused(const unsigned short* __restrict__ Qh, const unsigned short* __restrict__ Ql,
                const unsigned short* __restrict__ Vh, const unsigned short* __restrict__ Vl,
                const unsigned short* __restrict__ sT,
                float* __restrict__ gout, float* __restrict__ comb)
{
    extern __shared__ unsigned short lds[];
    // shorts layout: [0,36864)      stage buf0 (Qh 0 | Ql 2048 | Vh 4096 | Vl 20480)
    //                [36864,73728)  stage buf1 (same relative layout)
    //                [0,33280)      P[64][520]   (alias over buf0, post-K-loop)
    //                [73728,74752)  wred[64][8] f32
    //                [74752,74880)  rstat[64]   f32       => 149760 B total
    unsigned short* P = lds;
    float* wred  = (float*)(lds + 73728);
    float* rstat = (float*)(lds + 74752);

    const int tid  = threadIdx.x;
    const int lane = tid & 63, wave = tid >> 6;
    const int fr = lane & 15, kq = lane >> 4, k0 = kq * 8;
    const int wn = wave * 64;
    // swizzled reader chunk offset (phase 1 only)
    const int xk = (kq ^ (fr & 3)) * 8;

    const long b  = blockIdx.x;              // batch -> XCD (bid % 8)
    const long r0 = (long)blockIdx.y * 64;   // Q row block

    const unsigned short* Qhb = Qh + (b * 2048 + r0) * 1024;
    const unsigned short* Qlb = Ql + (b * 2048 + r0) * 1024;
    const unsigned short* Vhb = Vh + b * 512 * 1024;
    const unsigned short* Vlb = Vl + b * 512 * 1024;

    // ---- staging descriptors: 9 global_load_lds per wave per K-step -------
    // lane covers row (lane>>2) and 16B chunk (lane&3); SOURCE chunk is
    // pre-swizzled (c ^ row&3) so LDS stays linear (rule 21).
    const int drow = lane >> 2;
    const int scol = ((lane & 3) ^ (drow & 3)) * 8;
    const unsigned short* src[9];
    int dofs[9];  // LDS offset in shorts, relative to buffer base (wave-uniform)
    #pragma unroll
    for (int j = 0; j < 9; ++j) {
        const int is = wave * 9 + j;
        if (is < 4) {                         // Qh rows [16is,16is+16)
            src[j]  = Qhb + (is * 16 + drow) * 1024 + scol;
            dofs[j] = is * 512;
        } else if (is < 8) {
            const int q = is - 4;             // Ql
            src[j]  = Qlb + (q * 16 + drow) * 1024 + scol;
            dofs[j] = 2048 + q * 512;
        } else if (is < 40) {
            const int q = is - 8;             // Vh rows [16q,16q+16)
            src[j]  = Vhb + (q * 16 + drow) * 1024 + scol;
            dofs[j] = 4096 + q * 512;
        } else {
            const int q = is - 40;            // Vl
            src[j]  = Vlb + (q * 16 + drow) * 1024 + scol;
            dofs[j] = 20480 + q * 512;
        }
    }

    // ---------------- phase 1: S = Q @ V^T (split, pipelined) ----------------
    f32x4 acc[4][4] = {};

    // prologue: stage K-tile 0 into buf0
    #pragma unroll
    for (int j = 0; j < 9; ++j)
        __builtin_amdgcn_global_load_lds((gas_t)(src[j]),
                                         (las_t)(lds + dofs[j]), 16, 0, 0);

    #pragma unroll 2
    for (int t = 0; t < 32; ++t) {
        const int cur = (t & 1) * 36864;
        if (t < 31) {
            const int nxt = ((t + 1) & 1) * 36864;
            const int kb = (t + 1) * 32;
            #pragma unroll
            for (int j = 0; j < 9; ++j)
                __builtin_amdgcn_global_load_lds((gas_t)(src[j] + kb),
                                                 (las_t)(lds + nxt + dofs[j]), 16, 0, 0);
            asm volatile("s_waitcnt vmcnt(9)" ::: "memory");  // current tile's 9 done
        } else {
            asm volatile("s_waitcnt vmcnt(0)" ::: "memory");
        }
        __builtin_amdgcn_s_barrier();

        const unsigned short* QhL = lds + cur;
        const unsigned short* QlL = lds + cur + 2048;
        const unsigned short* VhL = lds + cur + 4096;
        const unsigned short* VlL = lds + cur + 20480;

        short8 ah[4], al[4], bh[4], bl[4];
        #pragma unroll
        for (int u = 0; u < 4; ++u) {
            ah[u] = *(const short8*)(QhL + (u * 16 + fr) * 32 + xk);
            al[u] = *(const short8*)(QlL + (u * 16 + fr) * 32 + xk);
            bh[u] = *(const short8*)(VhL + (wn + u * 16 + fr) * 32 + xk);
            bl[u] = *(const short8*)(VlL + (wn + u * 16 + fr) * 32 + xk);
        }
        #pragma unroll
        for (int mt = 0; mt < 4; ++mt)
            #pragma unroll
            for (int nt = 0; nt < 4; ++nt) {
                acc[mt][nt] = __builtin_amdgcn_mfma_f32_16x16x32_bf16(ah[mt], bh[nt], acc[mt][nt], 0, 0, 0);
                acc[mt][nt] = __builtin_amdgcn_mfma_f32_16x16x32_bf16(al[mt], bh[nt], acc[mt][nt], 0, 0, 0);
                acc[mt][nt] = __builtin_amdgcn_mfma_f32_16x16x32_bf16(ah[mt], bl[nt], acc[mt][nt], 0, 0, 0);
            }
        // all ds_reads consumed by MFMAs (compiler-inserted lgkmcnt); fence
        // and barrier before next iteration's stage overwrites this buffer
        asm volatile("s_waitcnt lgkmcnt(0)" ::: "memory");
        __builtin_amdgcn_s_barrier();
    }

    // ---------------- phase 2: exact row softmax ----------------
    // lane holds rows {mt*16+kq*4+i}, cols {64*wave + nt*16 + fr}
    float rmx[4][4];
    #pragma unroll
    for (int mt = 0; mt < 4; ++mt)
        #pragma unroll
        for (int i = 0; i < 4; ++i) {
            float m = fmaxf(fmaxf(acc[mt][0][i], acc[mt][1][i]),
                            fmaxf(acc[mt][2][i], acc[mt][3][i]));
            #pragma unroll
            for (int off = 1; off <= 8; off <<= 1)
                m = fmaxf(m, __shfl_xor(m, off));      // reduce over fr (bits 0-3)
            rmx[mt][i] = m;
        }
    if (fr == 0) {
        #pragma unroll
        for (int mt = 0; mt < 4; ++mt)
            #pragma unroll
            for (int i = 0; i < 4; ++i)
                wred[(mt * 16 + kq * 4 + i) * 8 + wave] = rmx[mt][i];
    }
    __syncthreads();
    if (tid < 64) {
        float m = wred[tid * 8];
        #pragma unroll
        for (int w = 1; w < 8; ++w) m = fmaxf(m, wred[tid * 8 + w]);
        rstat[tid] = m;
    }
    __syncthreads();

    #pragma unroll
    for (int mt = 0; mt < 4; ++mt)
        #pragma unroll
        for (int i = 0; i < 4; ++i) {
            const float m = rstat[mt * 16 + kq * 4 + i];
            float s = 0.f;
            #pragma unroll
            for (int nt = 0; nt < 4; ++nt) {
                const float e = __expf(acc[mt][nt][i] - m);
                acc[mt][nt][i] = e;
                s += e;
            }
            #pragma unroll
            for (int off = 1; off <= 8; off <<= 1) s += __shfl_xor(s, off);
            rmx[mt][i] = s;   // wave-partial sums
        }
    if (fr == 0) {
        #pragma unroll
        for (int mt = 0; mt < 4; ++mt)
            #pragma unroll
            for (int i = 0; i < 4; ++i)
                wred[(mt * 16 + kq * 4 + i) * 8 + wave] = rmx[mt][i];
    }
    __syncthreads();
    if (tid < 64) {
        float s = wred[tid * 8];
        #pragma unroll
        for (int w = 1; w < 8; ++w) s += wred[tid * 8 + w];
        rstat[tid] = 1.0f / s;   // overwrite rmax (all reads done)
    }
    __syncthreads();

    // ---------------- phase 3: P (bf16) -> LDS (aliases buf0) ----------------
    #pragma unroll
    for (int mt = 0; mt < 4; ++mt)
        #pragma unroll
        for (int i = 0; i < 4; ++i) {
            const int row = mt * 16 + kq * 4 + i;
            const float inv = rstat[row];
            #pragma unroll
            for (int nt = 0; nt < 4; ++nt)
                P[row * 520 + wn + nt * 16 + fr] = f2bf(acc[mt][nt][i] * inv);
        }
    __syncthreads();

    // ---------------- phase 4: G = P @ sentT^T ----------------
    const unsigned short* sTb = sT + b * 1024 * 512;
    const int e0 = wave * 128;
    const unsigned short* sb = sTb + (long)(e0 + fr) * 512 + k0;
    const unsigned short* pP = P + fr * 520 + k0;

    f32x4 acc2[4][8] = {};
    #pragma unroll 2
    for (int kb = 0; kb < 512; kb += 32) {
        short8 pa[4], pb[8];
        #pragma unroll
        for (int mt = 0; mt < 4; ++mt)
            pa[mt] = *(const short8*)(pP + mt * 16 * 520 + kb);
        #pragma unroll
        for (int nt = 0; nt < 8; ++nt)
            pb[nt] = *(const short8*)(sb + nt * 16 * 512 + kb);
        #pragma unroll
        for (int mt = 0; mt < 4; ++mt)
            #pragma unroll
            for (int nt = 0; nt < 8; ++nt)
                acc2[mt][nt] = __builtin_amdgcn_mfma_f32_16x16x32_bf16(pa[mt], pb[nt], acc2[mt][nt], 0, 0, 0);
    }

    float* gb = gout + (b * 2048 + r0) * 1024;
    float* cb = comb + (b * 2048 + r0) * 2048 + 1024;
    #pragma unroll
    for (int mt = 0; mt < 4; ++mt) {
        const int rowb = mt * 16 + kq * 4;
        #pragma unroll
        for (int nt = 0; nt < 8; ++nt) {
            const int col = e0 + nt * 16 + fr;
            #pragma unroll
            for (int i = 0; i < 4; ++i) {
                const float v = acc2[mt][nt][i];
                gb[(long)(rowb + i) * 1024 + col] = v;
                cb[(long)(rowb + i) * 2048 + col] = v;
            }
        }
    }
}

// ============================ FALLBACK PATH (round-1) ========================

template<bool SPLIT>
__global__ __launch_bounds__(256, 2)
void gemm_bt(const float* __restrict__ A, long sA, int lda,
             const float* __restrict__ B, long sB, int ldb,
             float* __restrict__ C, long sC, int ldc,
             float* __restrict__ C2, long sC2, int ldc2,
             int K)
{
    constexpr int LDS_S = 40;
    extern __shared__ unsigned short lds[];
    unsigned short* Ah = lds;
    unsigned short* Bh = lds + 128 * LDS_S;
    unsigned short* Al = SPLIT ? (lds + 2 * 128 * LDS_S) : nullptr;
    unsigned short* Bl = SPLIT ? (lds + 3 * 128 * LDS_S) : nullptr;

    const int tid = threadIdx.x;
    const int bz = blockIdx.z;
    A += (long)bz * sA; B += (long)bz * sB; C += (long)bz * sC;
    if (C2) C2 += (long)bz * sC2;
    const long m0 = (long)blockIdx.x * 128;
    const long n0 = (long)blockIdx.y * 128;

    const int lane = tid & 63, wave = tid >> 6;
    const int wm = (wave >> 1) * 64, wn = (wave & 1) * 64;
    const int fr = lane & 15, kq = lane >> 4, k0 = kq * 8;
    const int sc4 = (tid & 7) * 4;
    const int sr  = tid >> 3;

    f32x4 acc[4][4] = {};

    for (int kb = 0; kb < K; kb += 32) {
        #pragma unroll
        for (int p = 0; p < 4; ++p) {
            const int row = p * 32 + sr;
            const float4 va = *(const float4*)(A + (m0 + row) * lda + kb + sc4);
            const float4 vb = *(const float4*)(B + (n0 + row) * ldb + kb + sc4);
            u16x4 ah; ah[0] = f2bf(va.x); ah[1] = f2bf(va.y); ah[2] = f2bf(va.z); ah[3] = f2bf(va.w);
            u16x4 bh; bh[0] = f2bf(vb.x); bh[1] = f2bf(vb.y); bh[2] = f2bf(vb.z); bh[3] = f2bf(vb.w);
            *(u16x4*)(Ah + row * LDS_S + sc4) = ah;
            *(u16x4*)(Bh + row * LDS_S + sc4) = bh;
            if constexpr (SPLIT) {
                u16x4 al; al[0] = f2bf(va.x - bf2f(ah[0])); al[1] = f2bf(va.y - bf2f(ah[1]));
                          al[2] = f2bf(va.z - bf2f(ah[2])); al[3] = f2bf(va.w - bf2f(ah[3]));
                u16x4 bl; bl[0] = f2bf(vb.x - bf2f(bh[0])); bl[1] = f2bf(vb.y - bf2f(bh[1]));
                          bl[2] = f2bf(vb.z - bf2f(bh[2])); bl[3] = f2bf(vb.w - bf2f(bh[3]));
                *(u16x4*)(Al + row * LDS_S + sc4) = al;
                *(u16x4*)(Bl + row * LDS_S + sc4) = bl;
            }
        }
        __syncthreads();

        short8 af[4], bfr[4], alf[4], blf[4];
        #pragma unroll
        for (int t = 0; t < 4; ++t) {
            af[t]  = *(const short8*)(Ah + (wm + t * 16 + fr) * LDS_S + k0);
            bfr[t] = *(const short8*)(Bh + (wn + t * 16 + fr) * LDS_S + k0);
            if constexpr (SPLIT) {
                alf[t] = *(const short8*)(Al + (wm + t * 16 + fr) * LDS_S + k0);
                blf[t] = *(const short8*)(Bl + (wn + t * 16 + fr) * LDS_S + k0);
            }
        }
        #pragma unroll
        for (int mt = 0; mt < 4; ++mt)
            #pragma unroll
            for (int nt = 0; nt < 4; ++nt) {
                acc[mt][nt] = __builtin_amdgcn_mfma_f32_16x16x32_bf16(af[mt], bfr[nt], acc[mt][nt], 0, 0, 0);
                if constexpr (SPLIT) {
                    acc[mt][nt] = __builtin_amdgcn_mfma_f32_16x16x32_bf16(alf[mt], bfr[nt], acc[mt][nt], 0, 0, 0);
                    acc[mt][nt] = __builtin_amdgcn_mfma_f32_16x16x32_bf16(af[mt], blf[nt], acc[mt][nt], 0, 0, 0);
                }
            }
        __syncthreads();
    }

    #pragma unroll
    for (int mt = 0; mt < 4; ++mt) {
        const long rowb = m0 + wm + mt * 16 + kq * 4;
        #pragma unroll
        for (int nt = 0; nt < 4; ++nt) {
            const long col = n0 + wn + nt * 16 + fr;
            #pragma unroll
            for (int i = 0; i < 4; ++i) {
                C[(rowb + i) * ldc + col] = acc[mt][nt][i];
                if (C2) C2[(rowb + i) * ldc2 + col] = acc[mt][nt][i];
            }
        }
    }
}

__global__ __launch_bounds__(256)
void softmax_rows(float* __restrict__ S)
{
    const int wave = threadIdx.x >> 6, lane = threadIdx.x & 63;
    const long row = (long)blockIdx.x * 4 + wave;
    float* p = S + row * 512 + lane * 8;
    float4 v0 = *(float4*)p;
    float4 v1 = *(float4*)(p + 4);
    float m = fmaxf(fmaxf(fmaxf(v0.x, v0.y), fmaxf(v0.z, v0.w)),
                    fmaxf(fmaxf(v1.x, v1.y), fmaxf(v1.z, v1.w)));
    #pragma unroll
    for (int off = 32; off > 0; off >>= 1) m = fmaxf(m, __shfl_xor(m, off));
    v0.x = __expf(v0.x - m); v0.y = __expf(v0.y - m);
    v0.z = __expf(v0.z - m); v0.w = __expf(v0.w - m);
    v1.x = __expf(v1.x - m); v1.y = __expf(v1.y - m);
    v1.z = __expf(v1.z - m); v1.w = __expf(v1.w - m);
    float s = v0.x + v0.y + v0.z + v0.w + v1.x + v1.y + v1.z + v1.w;
    #pragma unroll
    for (int off = 32; off > 0; off >>= 1) s += __shfl_xor(s, off);
    const float inv = 1.0f / s;
    v0.x *= inv; v0.y *= inv; v0.z *= inv; v0.w *= inv;
    v1.x *= inv; v1.y *= inv; v1.z *= inv; v1.w *= inv;
    *(float4*)p = v0;
    *(float4*)(p + 4) = v1;
}

__global__ void transpose_bn(const float* __restrict__ in, float* __restrict__ out)
{
    __shared__ float tile[32][33];
    const int b = blockIdx.z;
    const int n0 = blockIdx.x * 32, e0 = blockIdx.y * 32;
    const float* src = in + (long)b * 512 * 1024;
    float* dst = out + (long)b * 1024 * 512;
    const int tx = threadIdx.x, ty = threadIdx.y;
    for (int i = ty; i < 32; i += 8)
        tile[i][tx] = src[(long)(n0 + i) * 1024 + e0 + tx];
    __syncthreads();
    for (int i = ty; i < 32; i += 8)
        dst[(long)(e0 + i) * 512 + n0 + tx] = tile[tx][i];
}

// ============================ LAUNCH ========================================

extern "C" void kernel_launch(void* const* d_in, const int* in_sizes, int n_in,
                              void* d_out, int out_size, void* d_ws, size_t ws_size,
                              hipStream_t stream)
{
    const float* word = (const float*)d_in[0];  // (8,2048,1024)
    const float* sent = (const float*)d_in[1];  // (8,512,1024)
    const float* W    = (const float*)d_in[2];  // (1024,1024)
    float* out  = (float*)d_out;
    float* comb = out;                              // (8,2048,2048)
    float* gout = out + (long)8 * 2048 * 2048;      // (8,2048,1024)

    const size_t MB = 1ull << 20;

    if (ws_size >= 110 * MB) {
        // -------- fast path: V = sent@W re-decomposition + fused attention --------
        char* w8 = (char*)d_ws;
        unsigned short* word_h = (unsigned short*)(w8);             // 32 MB [0,32)
        unsigned short* word_l = (unsigned short*)(w8 + 32 * MB);   // 32 MB [32,64)
        unsigned short* V_h    = (unsigned short*)(w8 + 64 * MB);   //  8 MB [64,72)
        unsigned short* V_l    = (unsigned short*)(w8 + 72 * MB);   //  8 MB [72,80)
        unsigned short* sentT  = (unsigned short*)(w8 + 80 * MB);   //  8 MB [80,88)
        unsigned short* sent_h = (unsigned short*)(w8 + 88 * MB);   //  8 MB [88,96)  dead after V-GEMM
        unsigned short* sent_l = (unsigned short*)(w8 + 96 * MB);   //  8 MB [96,104) dead after V-GEMM
        unsigned short* W_h    = (unsigned short*)(w8 + 104 * MB);  //  2 MB [104,106)
        unsigned short* Wt_h   = (unsigned short*)(w8 + 106 * MB);  //  2 MB [106,108)
        unsigned short* Wt_l   = (unsigned short*)(w8 + 108 * MB);  //  2 MB [108,110)

        // one-time: allow >64KB dynamic LDS for attn_fused (gfx950 has 160KB/CU)
        static bool attr_done = false;
        if (!attr_done) {
            (void)hipFuncSetAttribute((const void*)attn_fused,
                                      hipFuncAttributeMaxDynamicSharedMemorySize, 149760);
            attr_done = true;
        }

        convert_hl<<<16384, 256, 0, stream>>>(word, word_h, word_l);
        prep_W<<<dim3(32, 32), dim3(32, 8), 0, stream>>>(W, W_h, Wt_h, Wt_l);
        prep_sent<<<dim3(16, 32, 8), dim3(32, 8), 0, stream>>>(sent, sent_h, sent_l, sentT);

        const size_t lds4 = 4 * 128 * 32 * sizeof(unsigned short);  // 32 KB
        const size_t lds2 = 2 * 128 * 32 * sizeof(unsigned short);  // 16 KB

        // w = word @ W^T (PLAIN bf16) -> comb[:, :, 0:1024]
        gemm_k<false, false><<<dim3(128, 8, 1), 256, lds2, stream>>>(
            word_h, nullptr, 0L, 1024, W_h, nullptr, 0L, 1024,
            comb, 0L, 2048, nullptr, 0L, 0, nullptr, nullptr, 0L, 0, 1024);

        // V = sent @ W (SPLIT), batches merged in M (4096x1024), B=Wt shared
        gemm_k<true, true><<<dim3(32, 8, 1), 256, lds4, stream>>>(
            sent_h, sent_l, 0L, 1024, Wt_h, Wt_l, 0L, 1024,
            nullptr, 0L, 0, nullptr, 0L, 0, V_h, V_l, 0L, 1024, 1024);

        // fused: scores = word@V^T (split) -> softmax -> g = att@sent
        //        -> gout AND comb[:, :, 1024:2048]
        attn_fused<<<dim3(8, 32, 1), 512, 149760, stream>>>(
            word_h, word_l, V_h, V_l, sentT, gout, comb);
    } else {
        // -------- round-1 fallback (48 MB ws) --------
        float* scores = (float*)d_ws;                   // 32 MB
        float* sentT  = scores + (long)8 * 2048 * 512;  // 16 MB
        const size_t lds_split  = 4 * 128 * 40 * sizeof(unsigned short);
        const size_t lds_single = 2 * 128 * 40 * sizeof(unsigned short);

        transpose_bn<<<dim3(16, 32, 8), dim3(32, 8), 0, stream>>>(sent, sentT);
        gemm_bt<true><<<dim3(128, 8, 1), 256, lds_split, stream>>>(
            word, 0L, 1024, W, 0L, 1024, comb, 0L, 2048, nullptr, 0L, 0, 1024);
        gemm_bt<true><<<dim3(16, 4, 8), 256, lds_split, stream>>>(
            comb, (long)2048 * 2048, 2048, sent, (long)512 * 1024, 1024,
            scores, (long)2048 * 512, 512, nullptr, 0L, 0, 1024);
        softmax_rows<<<4096, 256, 0, stream>>>(scores);
        gemm_bt<false><<<dim3(16, 8, 8), 256, lds_single, stream>>>(
            scores, (long)2048 * 512, 512, sentT, (long)1024 * 512, 512,
            gout, (long)2048 * 1024, 1024, comb + 1024, (long)2048 * 2048, 2048, 512);
    }
}